// Round 9
// baseline (2652.831 us; speedup 1.0000x reference)
//
#include <hip/hip_runtime.h>
#include <cstddef>

#define TT 16
#define EE 80000
#define NB 768
#define NCHUNK 157          // ceil(2500/16)
#define NTILE 313           // ceil(5000/16)
#define XT_PAR 320512       // 5008*64
#define AS_PAR 20032        // 5008*4
#define WBLK 258048
#define O_LINH 0
#define O_LINL 12288
#define O_WIHH 24576
#define O_WIHL 73728
#define O_WHHH 122880
#define O_WHHL 172032
#define O_W1H  221184
#define O_W1L  239616
#define XCCREG 6164         // HW_REG_XCC_ID: id=20 | off=0<<6 | (4-1)<<11

typedef __attribute__((ext_vector_type(8))) short bf16x8;
typedef __attribute__((ext_vector_type(4))) float f32x4;

__device__ __forceinline__ float sigf(float x) { return 1.0f / (1.0f + __expf(-x)); }
__device__ __forceinline__ float lreluf(float x) { return x > 0.0f ? x : 0.2f * x; }

__device__ __forceinline__ unsigned short f2bf(float x) {
  union { float f; unsigned u; } v; v.f = x;
  unsigned r = v.u + 0x7FFF + ((v.u >> 16) & 1);
  return (unsigned short)(r >> 16);
}
__device__ __forceinline__ float bf2f(unsigned short u) {
  union { unsigned u; float f; } v; v.u = ((unsigned)u) << 16; return v.f;
}
__device__ __forceinline__ unsigned short f2h(float x) {
  _Float16 h = (_Float16)x;
  return __builtin_bit_cast(unsigned short, h);
}
__device__ __forceinline__ float h2f(unsigned short u) {
  return (float)__builtin_bit_cast(_Float16, u);
}
__device__ __forceinline__ f32x4 mfma16(bf16x8 a, bf16x8 b, f32x4 c) {
  return __builtin_amdgcn_mfma_f32_16x16x32_bf16(a, b, c, 0, 0, 0);
}
__device__ __forceinline__ void split8(const float* s, bf16x8& th, bf16x8& tl) {
#pragma unroll
  for (int i = 0; i < 8; ++i) {
    float v = s[i];
    unsigned short h = f2bf(v);
    th[i] = (short)h;
    tl[i] = (short)f2bf(v - bf2f(h));
  }
}
// agent-scope helpers: ONLY for setup/barrier words (bypass L2 — expensive)
__device__ __forceinline__ int ldi(const int* p) {
  return __hip_atomic_load((int*)p, __ATOMIC_RELAXED, __HIP_MEMORY_SCOPE_AGENT);
}

struct P {
  const float *x_seq, *att_src, *att_dst, *gat_bias, *ln_g, *ln_b, *b1, *w2, *b2;
  const float *lin_w, *w_ih, *w_hh, *b_ih, *b_hh, *w1;
  const int* eidx;
  float* out;
  unsigned short* xt;     // [8][4][XT_PAR]  (buf: cell0par0, cell0par1, cell1, cell2)
  float *as, *ad;         // [8][4][AS_PAR]
  unsigned short* wblk;   // [8][WBLK]
  float* bsum;            // [8][768]
  int *deg, *cnt, *startp, *adj;   // per-XCD CSR
  int *reg, *gcnt, *ggen, *g0;
};

// ---- fence-free monotonic barrier; data visibility via write-through L2 + syncthreads drain ----
__device__ __forceinline__ void mbar(int* cnt, int* gen, int size, int& rnd) {
  __syncthreads();                 // drains vmcnt of all waves -> stores in L2
  ++rnd;
  if (threadIdx.x == 0) {
    int v = __hip_atomic_fetch_add(cnt, 1, __ATOMIC_RELAXED, __HIP_MEMORY_SCOPE_AGENT) + 1;
    if (v == size * rnd) {
      __hip_atomic_store(gen, rnd, __ATOMIC_RELAXED, __HIP_MEMORY_SCOPE_AGENT);
    } else {
      while (__hip_atomic_load(gen, __ATOMIC_RELAXED, __HIP_MEMORY_SCOPE_AGENT) < rnd)
        __builtin_amdgcn_s_sleep(4);
    }
  }
  __builtin_amdgcn_fence(__ATOMIC_ACQUIRE, "workgroup");   // compiler ordering only
  __syncthreads();
}

// ---- phase A: xt GEMM (split bf16) + attention coefficients ----
__device__ void phaseA(const float* xbase, const unsigned short* linH, const unsigned short* linL,
                       const float* attS, const float* attD,
                       unsigned short* xtC, float* asC, float* adC, int rb, int lane) {
  const int l15 = lane & 15, lg = lane >> 4;
  int gm = rb * 16 + l15; if (gm > 4999) gm = 4999;
  const float* arow = xbase + (size_t)gm * 64;
  bf16x8 aH[2], aL[2];
#pragma unroll
  for (int ch = 0; ch < 2; ++ch) {
    float4 u0 = *reinterpret_cast<const float4*>(arow + ch * 32 + lg * 8);
    float4 u1 = *reinterpret_cast<const float4*>(arow + ch * 32 + lg * 8 + 4);
    float v[8] = {u0.x, u0.y, u0.z, u0.w, u1.x, u1.y, u1.z, u1.w};
    bf16x8 th, tl;
#pragma unroll
    for (int i = 0; i < 8; ++i) {
      unsigned short hi = f2bf(v[i]);
      th[i] = (short)hi;
      tl[i] = (short)f2bf(v[i] - bf2f(hi));
    }
    aH[ch] = th; aL[ch] = tl;
  }
  f32x4 acc[4];
#pragma unroll
  for (int nf = 0; nf < 4; ++nf) acc[nf] = (f32x4){0.f, 0.f, 0.f, 0.f};
#pragma unroll
  for (int nf = 0; nf < 4; ++nf) {
#pragma unroll
    for (int ch = 0; ch < 2; ++ch) {
      size_t wo = (size_t)(nf * 16 + l15) * 64 + ch * 32 + lg * 8;
      bf16x8 bH = *reinterpret_cast<const bf16x8*>(linH + wo);
      bf16x8 bL = *reinterpret_cast<const bf16x8*>(linL + wo);
      acc[nf] = mfma16(aH[ch], bH, acc[nf]);
      acc[nf] = mfma16(aH[ch], bL, acc[nf]);
      acc[nf] = mfma16(aL[ch], bH, acc[nf]);
    }
  }
#pragma unroll
  for (int nf = 0; nf < 4; ++nf) {
    float sv = attS[nf * 16 + l15], dv = attD[nf * 16 + l15];
#pragma unroll
    for (int r = 0; r < 4; ++r) {
      int row = rb * 16 + lg * 4 + r;
      float v = acc[nf][r];
      float ps = v * sv, pd = v * dv;
#pragma unroll
      for (int off = 1; off < 16; off <<= 1) { ps += __shfl_xor(ps, off); pd += __shfl_xor(pd, off); }
      xtC[(size_t)row * 64 + nf * 16 + l15] = f2h(v);
      if (l15 == 0) { asC[row * 4 + nf] = ps; adC[row * 4 + nf] = pd; }
    }
  }
}

// ---- gather one node: single-pass softmax, alpha staged in LDS, plain cached loads ----
__device__ void gather_node(const int* startp, const int* adj,
                            const float* asr, const float* adt, const unsigned short* xtC,
                            const float* gbias, int nh, int half, int lane,
                            float* sprow, float* alds, int* slds) {
  int s0 = startp[nh];
  int dg = startp[nh + 1] - s0;
  int nloc = half * 2500 + nh;
  float4 adv = *reinterpret_cast<const float4*>(adt + (size_t)nloc * 4);

  float ex0 = 0.f, ex1 = 0.f, ex2 = 0.f, ex3 = 0.f;
  int src0 = 0;
  if (lane < dg) {
    src0 = adj[s0 + lane];
    float4 av = *reinterpret_cast<const float4*>(asr + (size_t)src0 * 4);
    ex0 = __expf(lreluf(av.x + adv.x));
    ex1 = __expf(lreluf(av.y + adv.y));
    ex2 = __expf(lreluf(av.z + adv.z));
    ex3 = __expf(lreluf(av.w + adv.w));
  }
  float dn0 = ex0, dn1 = ex1, dn2 = ex2, dn3 = ex3;
  for (int e = 64 + lane; e < dg; e += 64) {
    int src = adj[s0 + e];
    float4 av = *reinterpret_cast<const float4*>(asr + (size_t)src * 4);
    dn0 += __expf(lreluf(av.x + adv.x));
    dn1 += __expf(lreluf(av.y + adv.y));
    dn2 += __expf(lreluf(av.z + adv.z));
    dn3 += __expf(lreluf(av.w + adv.w));
  }
#pragma unroll
  for (int off = 1; off < 64; off <<= 1) {
    dn0 += __shfl_xor(dn0, off);
    dn1 += __shfl_xor(dn1, off);
    dn2 += __shfl_xor(dn2, off);
    dn3 += __shfl_xor(dn3, off);
  }
  float rd0 = 1.0f / (dn0 + 1e-16f), rd1 = 1.0f / (dn1 + 1e-16f);
  float rd2 = 1.0f / (dn2 + 1e-16f), rd3 = 1.0f / (dn3 + 1e-16f);
  if (lane < dg) {
    *reinterpret_cast<float4*>(alds + lane * 4) =
        make_float4(ex0 * rd0, ex1 * rd1, ex2 * rd2, ex3 * rd3);
    slds[lane] = src0;
  }
  const int g = lane >> 4, c = lane & 15, head = c >> 2;
  float a0 = 0.f, a1 = 0.f, a2 = 0.f, a3 = 0.f;
  int dglim = dg < 64 ? dg : 64;
  for (int e = g; e < dglim; e += 4) {
    float alpha = alds[e * 4 + head];
    int src = slds[e];
    ushort4 xv = *reinterpret_cast<const ushort4*>(xtC + (size_t)src * 64 + c * 4);
    a0 = fmaf(alpha, h2f(xv.x), a0);
    a1 = fmaf(alpha, h2f(xv.y), a1);
    a2 = fmaf(alpha, h2f(xv.z), a2);
    a3 = fmaf(alpha, h2f(xv.w), a3);
  }
  if (dg > 64) {
    float rdh = head == 0 ? rd0 : head == 1 ? rd1 : head == 2 ? rd2 : rd3;
    float adh = head == 0 ? adv.x : head == 1 ? adv.y : head == 2 ? adv.z : adv.w;
    for (int e = 64 + g; e < dg; e += 4) {
      int src = adj[s0 + e];
      float av = asr[(size_t)src * 4 + head];
      float alpha = __expf(lreluf(av + adh)) * rdh;
      ushort4 xv = *reinterpret_cast<const ushort4*>(xtC + (size_t)src * 64 + c * 4);
      a0 = fmaf(alpha, h2f(xv.x), a0);
      a1 = fmaf(alpha, h2f(xv.y), a1);
      a2 = fmaf(alpha, h2f(xv.z), a2);
      a3 = fmaf(alpha, h2f(xv.w), a3);
    }
  }
  a0 += __shfl_xor(a0, 16); a0 += __shfl_xor(a0, 32);
  a1 += __shfl_xor(a1, 16); a1 += __shfl_xor(a1, 32);
  a2 += __shfl_xor(a2, 16); a2 += __shfl_xor(a2, 32);
  a3 += __shfl_xor(a3, 16); a3 += __shfl_xor(a3, 32);
  if (g == 0) {
    float4 bz = *reinterpret_cast<const float4*>(gbias + c * 4);
    *reinterpret_cast<float4*>(sprow + c * 4) =
        make_float4(a0 + bz.x, a1 + bz.y, a2 + bz.z, a3 + bz.w);
  }
}

// ---- mix: all three streams split-bf16 from LDS f32; blend exact f32 ----
__device__ void mixcore(const unsigned short* w1H, const unsigned short* w1L,
                        const float* b1, const float* w2, const float* b2, float* out,
                        size_t grow0, int validrows, int t, int lane,
                        const float* hf, const float* hm, const float* hs) {
  const int l15 = lane & 15, lg = lane >> 4;
  bf16x8 aH[3][2], aL[3][2];
#pragma unroll
  for (int ch = 0; ch < 2; ++ch) {
    split8(hf + l15 * 68 + ch * 32 + lg * 8, aH[0][ch], aL[0][ch]);
    split8(hm + l15 * 68 + ch * 32 + lg * 8, aH[1][ch], aL[1][ch]);
    split8(hs + l15 * 68 + ch * 32 + lg * 8, aH[2][ch], aL[2][ch]);
  }
  f32x4 acc[6];
#pragma unroll
  for (int nf = 0; nf < 6; ++nf) acc[nf] = (f32x4){0.f, 0.f, 0.f, 0.f};
#pragma unroll
  for (int nf = 0; nf < 6; ++nf) {
#pragma unroll
    for (int s = 0; s < 3; ++s) {
#pragma unroll
      for (int ch = 0; ch < 2; ++ch) {
        size_t wo = (size_t)(nf * 16 + l15) * 192 + s * 64 + ch * 32 + lg * 8;
        bf16x8 bH = *reinterpret_cast<const bf16x8*>(w1H + wo);
        bf16x8 bL = *reinterpret_cast<const bf16x8*>(w1L + wo);
        acc[nf] = mfma16(aH[s][ch], bH, acc[nf]);
        acc[nf] = mfma16(aH[s][ch], bL, acc[nf]);
        acc[nf] = mfma16(aL[s][ch], bH, acc[nf]);
      }
    }
  }
#pragma unroll
  for (int r = 0; r < 4; ++r) {
    float p0 = 0.f, p1 = 0.f, p2 = 0.f;
#pragma unroll
    for (int nf = 0; nf < 6; ++nf) {
      int n = nf * 16 + l15;
      float hdv = fmaxf(acc[nf][r] + b1[n], 0.f);
      p0 = fmaf(hdv, w2[n], p0);
      p1 = fmaf(hdv, w2[96 + n], p1);
      p2 = fmaf(hdv, w2[192 + n], p2);
    }
#pragma unroll
    for (int off = 1; off < 16; off <<= 1) {
      p0 += __shfl_xor(p0, off); p1 += __shfl_xor(p1, off); p2 += __shfl_xor(p2, off);
    }
    float q0 = p0 + b2[0], q1 = p1 + b2[1], q2 = p2 + b2[2];
    float mx = fmaxf(q0, fmaxf(q1, q2));
    float e0 = __expf(q0 - mx), e1 = __expf(q1 - mx), e2 = __expf(q2 - mx);
    float rs = 1.0f / (e0 + e1 + e2);
    float w0 = e0 * rs, w1v = e1 * rs, w2v = e2 * rs;
    int r16 = lg * 4 + r;
    if (r16 < validrows) {
      size_t ob = ((grow0 + r16) * TT + t) * 64;
#pragma unroll
      for (int q = 0; q < 4; ++q) {
        int col = l15 + 16 * q;
        float vf = hf[r16 * 68 + col];
        float vm = hm[r16 * 68 + col];
        float vs = hs[r16 * 68 + col];
        out[ob + col] = w0 * vf + w1v * vm + w2v * vs;
      }
    }
  }
}

// ---- unified cell update: sp(LDS) + h(LDS) + c in registers ----
__device__ void phaseC(const unsigned short* WihH, const unsigned short* WihL,
                       const unsigned short* WhhH, const unsigned short* WhhL,
                       const float* bsum, const float* lng, const float* lnb,
                       float creg[4][4], int lane, const float* sp, float* h) {
  const int l15 = lane & 15, lg = lane >> 4;
  bf16x8 sH[2], sL[2], hHa[2], hLa[2];
#pragma unroll
  for (int ch = 0; ch < 2; ++ch) {
    split8(sp + l15 * 68 + ch * 32 + lg * 8, sH[ch], sL[ch]);
    split8(h + l15 * 68 + ch * 32 + lg * 8, hHa[ch], hLa[ch]);
  }
  f32x4 acc[16];
#pragma unroll
  for (int nf = 0; nf < 16; ++nf) acc[nf] = (f32x4){0.f, 0.f, 0.f, 0.f};
#pragma unroll
  for (int nf = 0; nf < 16; ++nf) {
#pragma unroll
    for (int ch = 0; ch < 2; ++ch) {
      size_t wo = (size_t)(nf * 16 + l15) * 64 + ch * 32 + lg * 8;
      bf16x8 bH = *reinterpret_cast<const bf16x8*>(WihH + wo);
      bf16x8 bL = *reinterpret_cast<const bf16x8*>(WihL + wo);
      acc[nf] = mfma16(sH[ch], bH, acc[nf]);
      acc[nf] = mfma16(sH[ch], bL, acc[nf]);
      acc[nf] = mfma16(sL[ch], bH, acc[nf]);
      bf16x8 cH = *reinterpret_cast<const bf16x8*>(WhhH + wo);
      bf16x8 cL = *reinterpret_cast<const bf16x8*>(WhhL + wo);
      acc[nf] = mfma16(hHa[ch], cH, acc[nf]);
      acc[nf] = mfma16(hHa[ch], cL, acc[nf]);
      acc[nf] = mfma16(hLa[ch], cH, acc[nf]);
    }
  }
  float hn[4][4];
#pragma unroll
  for (int cq = 0; cq < 4; ++cq) {
    int col = cq * 16 + l15;
    float bi = bsum[col], bff = bsum[64 + col], bg = bsum[128 + col], bo = bsum[192 + col];
#pragma unroll
    for (int r = 0; r < 4; ++r) {
      float gi = acc[cq][r] + bi;
      float gf = acc[cq + 4][r] + bff;
      float gg = acc[cq + 8][r] + bg;
      float go = acc[cq + 12][r] + bo;
      float cv = sigf(gf) * creg[cq][r] + sigf(gi) * tanhf(gg);
      creg[cq][r] = cv;
      hn[cq][r] = sigf(go) * tanhf(cv);
    }
  }
#pragma unroll
  for (int r = 0; r < 4; ++r) {
    float s = hn[0][r] + hn[1][r] + hn[2][r] + hn[3][r];
#pragma unroll
    for (int off = 1; off < 16; off <<= 1) s += __shfl_xor(s, off);
    float mu = s * (1.0f / 64.0f);
    float vv = 0.f;
#pragma unroll
    for (int cq = 0; cq < 4; ++cq) { float d = hn[cq][r] - mu; vv += d * d; }
#pragma unroll
    for (int off = 1; off < 16; off <<= 1) vv += __shfl_xor(vv, off);
    float rstd = rsqrtf(vv * (1.0f / 64.0f) + 1e-5f);
#pragma unroll
    for (int cq = 0; cq < 4; ++cq) {
      int col = cq * 16 + l15;
      h[(lg * 4 + r) * 68 + col] = (hn[cq][r] - mu) * rstd * lng[col] + lnb[col];
    }
  }
}

// ---- the mega kernel ----
__global__ __launch_bounds__(256, 3) void mega(P p) {
  const int tid = threadIdx.x, lane = tid & 63, wv = tid >> 6, pair = wv >> 1;
  __shared__ float s8[8][16][68];
  __shared__ float al[4][256];
  __shared__ int sr[4][64];
  __shared__ int shr[2];

  const int xcd = (int)(__builtin_amdgcn_s_getreg(XCCREG) & 7);
  if (tid == 0)
    shr[0] = (int)__hip_atomic_fetch_add(&p.reg[xcd], 1, __ATOMIC_RELAXED, __HIP_MEMORY_SCOPE_AGENT);

  int grnd = 0;
  mbar(p.g0, p.g0 + 16, NB, grnd);     // global: all registrations done
  if (tid == 0) shr[1] = ldi(&p.reg[xcd]);
  __syncthreads();
  const int rank = shr[0], size = shr[1];
  const int batch = xcd >> 1, half = xcd & 1;
  const size_t nodeg = (size_t)batch * 5000 + (size_t)half * 2500;

  unsigned short* xtX = p.xt + (size_t)xcd * 4 * XT_PAR;
  float* asX = p.as + (size_t)xcd * 4 * AS_PAR;
  float* adX = p.ad + (size_t)xcd * 4 * AS_PAR;
  unsigned short* w = p.wblk + (size_t)xcd * WBLK;
  float* bsum = p.bsum + xcd * 768;
  int* deg = p.deg + xcd * 2504;
  int* cnt = p.cnt + xcd * 2504;
  int* startp = p.startp + xcd * 2504;
  int* adj = p.adj + (size_t)xcd * 82504;
  int* xc = p.gcnt + xcd * 16;
  int* xg = p.ggen + xcd * 16;
  int xrnd = 0;

  for (int i = tid; i < 8 * 16 * 68; i += 256) ((float*)s8)[i] = 0.f;
  float cregF[4][4], cregM[4][4];
#pragma unroll
  for (int a = 0; a < 4; ++a)
#pragma unroll
    for (int r = 0; r < 4; ++r) { cregF[a][r] = 0.f; cregM[a][r] = 0.f; }

  const int st = rank * 256 + tid, stride = size * 256;

  // S0: CSR counters; split weights (per-XCD private copies)
  for (int i = st; i < 2504; i += stride) { deg[i] = 0; cnt[i] = 0; }
  for (int i = st; i < 49152; i += stride) {
    if (i < 12288) { float v = p.lin_w[i]; unsigned short h = f2bf(v); w[O_LINH + i] = h; w[O_LINL + i] = f2bf(v - bf2f(h)); }
    { float v = p.w_ih[i]; unsigned short h = f2bf(v); w[O_WIHH + i] = h; w[O_WIHL + i] = f2bf(v - bf2f(h)); }
    { float v = p.w_hh[i]; unsigned short h = f2bf(v); w[O_WHHH + i] = h; w[O_WHHL + i] = f2bf(v - bf2f(h)); }
    if (i < 18432) { float v = p.w1[i]; unsigned short h = f2bf(v); w[O_W1H + i] = h; w[O_W1L + i] = f2bf(v - bf2f(h)); }
    if (i < 768) bsum[i] = p.b_ih[i] + p.b_hh[i];
  }
  mbar(xc, xg, size, xrnd);

  // S1: degree count
  for (int i = st; i < EE + 2500; i += stride) {
    if (i < EE) {
      int dst = p.eidx[EE + i];
      if ((dst >= 2500) == (half == 1)) atomicAdd(deg + (dst - half * 2500), 1);
    } else atomicAdd(deg + (i - EE), 1);
  }
  mbar(xc, xg, size, xrnd);

  // S2: scan (rank-0 block of each XCD; agent loads for freshly-RMW'd deg)
  if (rank == 0) {
    int* ib = (int*)&al[0][0];
    int s = 0;
    for (int j = 0; j < 10; ++j) {
      int n = tid * 10 + j;
      if (n < 2500) s += ldi(deg + n);
    }
    ib[tid] = s;
    __syncthreads();
    for (int off = 1; off < 256; off <<= 1) {
      int tv = (tid >= off) ? ib[tid - off] : 0;
      __syncthreads();
      ib[tid] += tv;
      __syncthreads();
    }
    int excl = ib[tid] - s;
    for (int j = 0; j < 10; ++j) {
      int n = tid * 10 + j;
      if (n < 2500) { startp[n] = excl; excl += ldi(deg + n); }
    }
    if (tid == 255) startp[2500] = ib[255];
    __syncthreads();
  }
  mbar(xc, xg, size, xrnd);

  // S3: fill adjacency + A(t=0) for cells f,m,s  (bufs 0,2,3)
  for (int i = st; i < EE + 2500; i += stride) {
    if (i < EE) {
      int dst = p.eidx[EE + i];
      if ((dst >= 2500) == (half == 1)) {
        int ln = dst - half * 2500;
        int pos = atomicAdd(cnt + ln, 1);
        adj[startp[ln] + pos] = p.eidx[i];
      }
    } else {
      int n = i - EE;
      int pos = atomicAdd(cnt + n, 1);
      adj[startp[n] + pos] = half * 2500 + n;
    }
  }
  {
    const float* xb = p.x_seq + (size_t)batch * 5000 * 64;
    for (int a = rank * 4 + wv; a < 3 * NTILE; a += size * 4) {
      int cell = a / NTILE, rb = a - cell * NTILE;
      int buf = (cell == 0) ? 0 : cell + 1;
      phaseA(xb, w + O_LINH + cell * 4096, w + O_LINL + cell * 4096,
             p.att_src + cell * 64, p.att_dst + cell * 64,
             xtX + (size_t)buf * XT_PAR, asX + (size_t)buf * AS_PAR,
             adX + (size_t)buf * AS_PAR, rb, lane);
    }
  }
  mbar(xc, xg, size, xrnd);

  const int chunk = rank * 2 + pair;
  const bool has = chunk < NCHUNK;
  const int validrows = has ? ((2500 - chunk * 16) < 16 ? (2500 - chunk * 16) : 16) : 0;
  const size_t grow0 = nodeg + (size_t)chunk * 16;
  float* sp = &s8[pair * 4 + 0][0][0];
  float* hf = &s8[pair * 4 + 1][0][0];
  float* hm = &s8[pair * 4 + 2][0][0];
  float* hs = &s8[pair * 4 + 3][0][0];

  auto do_gather = [&](int cell, int buf) {
    if (!has) return;
    const float* asr = asX + (size_t)buf * AS_PAR;
    const float* adt = adX + (size_t)buf * AS_PAR;
    const unsigned short* xtC = xtX + (size_t)buf * XT_PAR;
    const float* gb = p.gat_bias + cell * 64;
    int w01 = wv & 1;
    for (int j = 0; j < 8; ++j) {
      int ridx = w01 * 8 + j;
      int nh = chunk * 16 + ridx;
      float* sprow = sp + ridx * 68;
      if (nh < 2500)
        gather_node(startp, adj, asr, adt, xtC, gb, nh, half, lane, sprow, &al[wv][0], &sr[wv][0]);
      else if ((lane >> 4) == 0)
        *reinterpret_cast<float4*>(sprow + (lane & 15) * 4) = make_float4(0.f, 0.f, 0.f, 0.f);
    }
  };

  const float* xb = p.x_seq + (size_t)batch * 5000 * 64;

  for (int t = 0; t < TT; ++t) {
    if (t != 0 && t != 15) {
      do_gather(0, t & 1);
      __syncthreads();
      if (wv & 1) {
        int nA = (t + 1 == 15) ? 2 * NTILE : NTILE;
        const float* xbt = xb + (size_t)(t + 1) * 20000 * 64;
        for (int a = rank * 2 + pair; a < nA; a += 2 * size) {
          int cell = a >= NTILE, rb = a - cell * NTILE;
          int buf = cell ? 2 : ((t + 1) & 1);
          phaseA(xbt, w + O_LINH + cell * 4096, w + O_LINL + cell * 4096,
                 p.att_src + cell * 64, p.att_dst + cell * 64,
                 xtX + (size_t)buf * XT_PAR, asX + (size_t)buf * AS_PAR,
                 adX + (size_t)buf * AS_PAR, rb, lane);
        }
      } else if (has) {
        phaseC(w + O_WIHH, w + O_WIHL, w + O_WHHH, w + O_WHHL,
               bsum, p.ln_g, p.ln_b, cregF, lane, sp, hf);
        mixcore(w + O_W1H, w + O_W1L, p.b1, p.w2, p.b2, p.out, grow0, validrows, t, lane, hf, hm, hs);
      }
    } else if (t == 0) {
      do_gather(0, 0);
      __syncthreads();
      if (has && !(wv & 1))
        phaseC(w + O_WIHH, w + O_WIHL, w + O_WHHH, w + O_WHHL,
               bsum, p.ln_g, p.ln_b, cregF, lane, sp, hf);
      __syncthreads();
      do_gather(1, 2);
      __syncthreads();
      if (has && !(wv & 1))
        phaseC(w + O_WIHH + 16384, w + O_WIHL + 16384, w + O_WHHH + 16384, w + O_WHHL + 16384,
               bsum + 256, p.ln_g + 64, p.ln_b + 64, cregM, lane, sp, hm);
      __syncthreads();
      do_gather(2, 3);
      __syncthreads();
      if (has && !(wv & 1)) {
        float cregS[4][4];
#pragma unroll
        for (int a = 0; a < 4; ++a)
#pragma unroll
          for (int r = 0; r < 4; ++r) cregS[a][r] = 0.f;
        phaseC(w + O_WIHH + 32768, w + O_WIHL + 32768, w + O_WHHH + 32768, w + O_WHHL + 32768,
               bsum + 512, p.ln_g + 128, p.ln_b + 128, cregS, lane, sp, hs);
        mixcore(w + O_W1H, w + O_W1L, p.b1, p.w2, p.b2, p.out, grow0, validrows, 0, lane, hf, hm, hs);
      }
      __syncthreads();
      const float* xbt = xb + (size_t)20000 * 64;   // t=1, cell0 -> buf1
      for (int a = rank * 4 + wv; a < NTILE; a += size * 4)
        phaseA(xbt, w + O_LINH, w + O_LINL, p.att_src, p.att_dst,
               xtX + XT_PAR, asX + AS_PAR, adX + AS_PAR, a, lane);
    } else {   // t == 15
      do_gather(0, 1);
      __syncthreads();
      if (has && !(wv & 1))
        phaseC(w + O_WIHH, w + O_WIHL, w + O_WHHH, w + O_WHHL,
               bsum, p.ln_g, p.ln_b, cregF, lane, sp, hf);
      __syncthreads();
      do_gather(1, 2);
      __syncthreads();
      if (has && !(wv & 1)) {
        phaseC(w + O_WIHH + 16384, w + O_WIHL + 16384, w + O_WHHH + 16384, w + O_WHHL + 16384,
               bsum + 256, p.ln_g + 64, p.ln_b + 64, cregM, lane, sp, hm);
        mixcore(w + O_W1H, w + O_W1L, p.b1, p.w2, p.b2, p.out, grow0, validrows, 15, lane, hf, hm, hs);
      }
    }
    mbar(xc, xg, size, xrnd);
  }
}

// ---- host side ----
extern "C" void kernel_launch(void* const* d_in, const int* in_sizes, int n_in,
                              void* d_out, int out_size, void* d_ws, size_t ws_size,
                              hipStream_t stream) {
  P p;
  p.x_seq    = (const float*)d_in[0];
  p.lin_w    = (const float*)d_in[1];
  p.att_src  = (const float*)d_in[2];
  p.att_dst  = (const float*)d_in[3];
  p.gat_bias = (const float*)d_in[4];
  p.w_ih     = (const float*)d_in[5];
  p.w_hh     = (const float*)d_in[6];
  p.b_ih     = (const float*)d_in[7];
  p.b_hh     = (const float*)d_in[8];
  p.ln_g     = (const float*)d_in[9];
  p.ln_b     = (const float*)d_in[10];
  p.w1       = (const float*)d_in[11];
  p.b1       = (const float*)d_in[12];
  p.w2       = (const float*)d_in[13];
  p.b2       = (const float*)d_in[14];
  p.eidx     = (const int*)d_in[15];
  p.out      = (float*)d_out;

  char* base = (char*)d_ws;
  size_t off = 0;
  auto alloc = [&](size_t bytes) { char* r = base + off; off += (bytes + 255) & ~(size_t)255; return r; };
  p.xt     = (unsigned short*)alloc((size_t)8 * 4 * XT_PAR * 2);
  p.as     = (float*)alloc((size_t)8 * 4 * AS_PAR * 4);
  p.ad     = (float*)alloc((size_t)8 * 4 * AS_PAR * 4);
  p.wblk   = (unsigned short*)alloc((size_t)8 * WBLK * 2);
  p.bsum   = (float*)alloc(8 * 768 * 4);
  p.deg    = (int*)alloc(8 * 2504 * 4);
  p.cnt    = (int*)alloc(8 * 2504 * 4);
  p.startp = (int*)alloc(8 * 2504 * 4);
  p.adj    = (int*)alloc((size_t)8 * 82504 * 4);
  int* barzone = (int*)alloc(8192);
  p.reg  = barzone;            // 8
  p.gcnt = barzone + 64;       // 8*16
  p.ggen = barzone + 64 + 128; // 8*16
  p.g0   = barzone + 64 + 256; // cnt at +0, gen at +16

  hipMemsetAsync(barzone, 0, 8192, stream);
  mega<<<NB, 256, 0, stream>>>(p);
}